// Round 7
// baseline (1317.609 us; speedup 1.0000x reference)
//
#include <hip/hip_runtime.h>
#include <hip/hip_bf16.h>

typedef __hip_bfloat16 bf16;
typedef __attribute__((ext_vector_type(8))) short short8;
typedef __attribute__((ext_vector_type(4))) short short4v;
typedef __attribute__((ext_vector_type(4))) float f32x4;

#define NB 128
#define NH 128
#define NLQ 128
#define NLD 512
#define NEMB 300

__device__ __forceinline__ unsigned short bfbits(float x) {
    __hip_bfloat16 h = __float2bfloat16(x);
    return *reinterpret_cast<unsigned short*>(&h);
}

__device__ __forceinline__ float fast_tanh(float x) {
    x = fminf(9.f, fmaxf(-9.f, x));
    float e = __builtin_amdgcn_exp2f(x * 2.8853900817779268f); // e^{2x}
    return (e - 1.f) * __builtin_amdgcn_rcpf(e + 1.f);
}

// ---------------- Stage 0: pack conv weights, cc-major: [cc][t][h][c'] ------
__global__ void pack_w(const float* __restrict__ cw0, const float* __restrict__ cw1,
                       const float* __restrict__ cw2, bf16* __restrict__ Wp)
{
    int widx = blockIdx.y;
    int W = widx + 2;
    int e = blockIdx.x * 256 + threadIdx.x;
    if (e >= W * 40960) return;
    int ch = e >> 12;            // chunk = 4096 bf16
    int cc = ch / W;
    int t  = ch - cc * W;
    int h  = (e >> 5) & 127;
    int cp = e & 31;
    int c  = cc * 32 + cp;
    const float* cw = (widx == 0) ? cw0 : (widx == 1 ? cw1 : cw2);
    float v = (c < NEMB) ? cw[(h * NEMB + c) * W + t] : 0.f;
    size_t off = (widx == 0) ? 0 : (widx == 1 ? 81920 : 204800);
    Wp[off + e] = __float2bfloat16(v);
}

// ---------------- Stage 1: gather + conv + tanh + l2norm ----------------
// 256(l)x128(h) tile, 8 waves (4r x 2c) of 64x64. A (gathered X) through LDS,
// single-buffered, 2 barriers per 32-col chunk. B (weights) read DIRECTLY from
// global Wp each step (1KB-contiguous per-wave fragments, L1/L2-resident) --
// no Bs LDS, no per-step barrier. LDS ~23KB -> 4 blocks/CU.
__global__ __launch_bounds__(512, 8)
void conv_kernel(const int* __restrict__ q_tok, const int* __restrict__ d_tok,
                 const float* __restrict__ q_emb, const float* __restrict__ d_emb,
                 const bf16* __restrict__ Wp,
                 const float* __restrict__ cb0, const float* __restrict__ cb1,
                 const float* __restrict__ cb2,
                 bf16* __restrict__ qn, bf16* __restrict__ dn)
{
    __shared__ bf16 Xs[2][132][40];      // [subtile][row][col]; single K-chunk buffer
    __shared__ int tokLds[2][132];
    __shared__ float ssq[2][256];

    int bx = blockIdx.x;
    int widx = bx % 3;
    int inner = bx / 3;
    int W = widx + 2;
    const bf16* wp = Wp + ((widx == 0) ? 0 : (widx == 1 ? 81920 : 204800));
    const float* cb = (widx == 0) ? cb0 : (widx == 1 ? cb1 : cb2);

    const int* toks; const float* emb; bf16* outp; int L;
    int sb0, sb1, sl00, sl01;
    if (inner < 64) {
        toks = q_tok; emb = q_emb; outp = qn + (size_t)widx * NB * NLQ * NH;
        L = NLQ; sb0 = inner * 2; sb1 = sb0 + 1; sl00 = 0; sl01 = 0;
    } else {
        int i = inner - 64;
        toks = d_tok; emb = d_emb; outp = dn + (size_t)widx * NB * NLD * NH;
        L = NLD; sb0 = i >> 1; sb1 = sb0; sl00 = (i & 1) * 256; sl01 = sl00 + 128;
    }

    int tid = threadIdx.x;
    int lane = tid & 63;
    int wv = tid >> 6;
    int wr = wv >> 1;     // 0..3 (row quarter)
    int wc = wv & 1;      // 0..1 (col half)
    int s_wave = wr >> 1;
    int lr_base = (wr & 1) * 64;

    // ---- tokens ----
    if (tid < 132) {
        int l = sl00 + tid;
        tokLds[0][tid] = (l < L) ? toks[sb0 * L + l] : -1;
    } else if (tid >= 256 && tid < 388) {
        int rr = tid - 256;
        int l = sl01 + rr;
        tokLds[1][rr] = (l < L) ? toks[sb1 * L + l] : -1;
    }
    __syncthreads();

    // ---- X staging helpers (main: 2 thr/row rows 0..255; tail: thr 448+ rows 128..131) ----
    auto xload_main = [&](int cc, float4* v) {
        int u = tid >> 1, s = u >> 7, rr = u & 127, half = tid & 1;
        int tok = tokLds[s][rr];
        int cbase = cc * 32 + half * 16;
        #pragma unroll
        for (int qq = 0; qq < 4; ++qq) {
            int c = cbase + qq * 4;
            float4 x = make_float4(0.f, 0.f, 0.f, 0.f);
            if (tok >= 0 && c < NEMB)
                x = *reinterpret_cast<const float4*>(emb + (size_t)tok * NEMB + c);
            v[qq] = x;
        }
    };
    auto xwrite_main = [&](const float4* v) {
        int u = tid >> 1, s = u >> 7, rr = u & 127, half = tid & 1;
        short8 o0, o1;
        o0[0] = (short)bfbits(v[0].x); o0[1] = (short)bfbits(v[0].y);
        o0[2] = (short)bfbits(v[0].z); o0[3] = (short)bfbits(v[0].w);
        o0[4] = (short)bfbits(v[1].x); o0[5] = (short)bfbits(v[1].y);
        o0[6] = (short)bfbits(v[1].z); o0[7] = (short)bfbits(v[1].w);
        o1[0] = (short)bfbits(v[2].x); o1[1] = (short)bfbits(v[2].y);
        o1[2] = (short)bfbits(v[2].z); o1[3] = (short)bfbits(v[2].w);
        o1[4] = (short)bfbits(v[3].x); o1[5] = (short)bfbits(v[3].y);
        o1[6] = (short)bfbits(v[3].z); o1[7] = (short)bfbits(v[3].w);
        *reinterpret_cast<short8*>(&Xs[s][rr][half * 16]) = o0;
        *reinterpret_cast<short8*>(&Xs[s][rr][half * 16 + 8]) = o1;
    };
    auto xload_tail = [&](int cc, float4& x) {
        int j = tid - 448, trow = j >> 3, s = trow >> 2, rr = 128 + (trow & 3), qq = j & 7;
        int tok = tokLds[s][rr];
        int c = cc * 32 + qq * 4;
        x = make_float4(0.f, 0.f, 0.f, 0.f);
        if (tok >= 0 && c < NEMB)
            x = *reinterpret_cast<const float4*>(emb + (size_t)tok * NEMB + c);
    };
    auto xwrite_tail = [&](const float4& x) {
        int j = tid - 448, trow = j >> 3, s = trow >> 2, rr = 128 + (trow & 3), qq = j & 7;
        short4v o;
        o[0] = (short)bfbits(x.x); o[1] = (short)bfbits(x.y);
        o[2] = (short)bfbits(x.z); o[3] = (short)bfbits(x.w);
        *reinterpret_cast<short4v*>(&Xs[s][rr][qq * 4]) = o;
    };

    // ---- prologue: stage X chunk 0 ----
    {
        float4 v[4];
        xload_main(0, v);
        float4 xt;
        if (tid >= 448) xload_tail(0, xt);
        xwrite_main(v);
        if (tid >= 448) xwrite_tail(xt);
    }
    __syncthreads();

    f32x4 acc[4][4];
    #pragma unroll
    for (int m = 0; m < 4; ++m)
        #pragma unroll
        for (int n = 0; n < 4; ++n)
            acc[m][n] = (f32x4){0.f, 0.f, 0.f, 0.f};

    const short8* wp8 = reinterpret_cast<const short8*>(wp);
    float4 xv[4]; float4 xtl;

    for (int cc = 0; cc < 10; ++cc) {
        if (cc < 9) {      // issue next-chunk gather early; consumed after t-loop
            xload_main(cc + 1, xv);
            if (tid >= 448) xload_tail(cc + 1, xtl);
        }
        for (int t = 0; t < W; ++t) {
            int so = (cc * W + t) * 512;
            short8 bv[4];
            #pragma unroll
            for (int n = 0; n < 4; ++n)
                bv[n] = wp8[so + (wc * 64 + n * 16 + (lane & 15)) * 4 + (lane >> 4)];
            #pragma unroll
            for (int m = 0; m < 4; ++m) {
                short8 af = *reinterpret_cast<const short8*>(
                    &Xs[s_wave][lr_base + m * 16 + (lane & 15) + t][(lane >> 4) * 8]);
                #pragma unroll
                for (int n = 0; n < 4; ++n)
                    acc[m][n] = __builtin_amdgcn_mfma_f32_16x16x32_bf16(af, bv[n], acc[m][n], 0, 0, 0);
            }
        }
        if (cc < 9) {
            __syncthreads();          // all waves done reading this chunk
            xwrite_main(xv);
            if (tid >= 448) xwrite_tail(xtl);
            __syncthreads();          // new chunk visible
        }
    }

    // ---- epilogue: bias + tanh, row l2norm, store ----
    float ssl[4][4];
    #pragma unroll
    for (int m = 0; m < 4; ++m)
        #pragma unroll
        for (int i = 0; i < 4; ++i) ssl[m][i] = 0.f;

    #pragma unroll
    for (int n = 0; n < 4; ++n) {
        float bias = cb[wc * 64 + n * 16 + (lane & 15)];
        #pragma unroll
        for (int m = 0; m < 4; ++m)
            #pragma unroll
            for (int i = 0; i < 4; ++i) {
                float v = fast_tanh(acc[m][n][i] + bias);
                acc[m][n][i] = v;
                ssl[m][i] += v * v;
            }
    }
    #pragma unroll
    for (int m = 0; m < 4; ++m)
        #pragma unroll
        for (int i = 0; i < 4; ++i) {
            float s = ssl[m][i];
            s += __shfl_xor(s, 1); s += __shfl_xor(s, 2);
            s += __shfl_xor(s, 4); s += __shfl_xor(s, 8);
            ssl[m][i] = s;
        }
    if ((lane & 15) == 0) {
        #pragma unroll
        for (int m = 0; m < 4; ++m)
            #pragma unroll
            for (int i = 0; i < 4; ++i)
                ssq[wc][wr * 64 + m * 16 + (lane >> 4) * 4 + i] = ssl[m][i];
    }
    __syncthreads();
    #pragma unroll
    for (int m = 0; m < 4; ++m)
        #pragma unroll
        for (int i = 0; i < 4; ++i) {
            int r = wr * 64 + m * 16 + (lane >> 4) * 4 + i;
            float s2 = ssq[0][r] + ssq[1][r];
            float sc = 1.f / fmaxf(sqrtf(s2), 1e-12f);
            int s = r >> 7, lr = r & 127;
            int b = s ? sb1 : sb0;
            int l = (s ? sl01 : sl00) + lr;
            bf16* dst = outp + ((size_t)(b * L + l)) * NH;
            #pragma unroll
            for (int n = 0; n < 4; ++n)
                dst[wc * 64 + n * 16 + (lane & 15)] = __float2bfloat16(acc[m][n][i] * sc);
        }
}

// ---------------- Stage 2: S^T = D*Q^T, recurrence pooling ----------
// 8 chunks of 64 d-rows; red aliases Ds; LDS ~52.3KB -> 3 blocks/CU.
__global__ __launch_bounds__(256, 4)
void sim_kernel(const bf16* __restrict__ qn, const bf16* __restrict__ dn,
                float* __restrict__ phi)
{
    __shared__ bf16 Qs[128][136];
    __shared__ bf16 Ds[64][136];
    __shared__ float wsum[2][11];
    float (*red)[128][11] = reinterpret_cast<float(*)[128][11]>(&Ds[0][0]); // alias (disjoint in time)

    int blk = blockIdx.x;
    int b = blk / 9;
    int pair = blk - b * 9;
    int qi = pair / 3, di = pair - qi * 3;

    int tid = threadIdx.x, lane = tid & 63, wv = tid >> 6, wr = wv >> 1, wc = wv & 1;

    const bf16* qbase = qn + ((size_t)qi * NB + b) * (NLQ * NH);
    const bf16* dbase = dn + ((size_t)di * NB + b) * (NLD * NH);

    // stage Q (128x128): 2 thr/row
    {
        int r = tid >> 1, h0 = (tid & 1) * 64;
        #pragma unroll
        for (int v = 0; v < 8; ++v)
            *reinterpret_cast<short8*>(&Qs[r][h0 + v * 8]) =
                *reinterpret_cast<const short8*>(qbase + (size_t)r * NH + h0 + v * 8);
    }

    // stage D chunk 0 (64 rows): 4 thr/row
    int dr = tid >> 2, dc = (tid & 3) * 32;
    {
        short8 st[4];
        #pragma unroll
        for (int v = 0; v < 4; ++v)
            st[v] = *reinterpret_cast<const short8*>(dbase + (size_t)dr * NH + dc + v * 8);
        #pragma unroll
        for (int v = 0; v < 4; ++v)
            *reinterpret_cast<short8*>(&Ds[dr][dc + v * 8]) = st[v];
    }
    __syncthreads();

    float sums[4][11];
    #pragma unroll
    for (int n = 0; n < 4; ++n)
        #pragma unroll
        for (int k = 0; k < 11; ++k) sums[n][k] = 0.f;

    const float C1 = 1.8315638888734179e-2f;   // e^-4
    const float C2 = 3.3546262790251185e-4f;   // e^-8
    const float C3 = 6.1442123533282098e-6f;   // e^-12
    const float C4 = 1.1253517471925912e-7f;   // e^-16

    for (int cc = 0; cc < 8; ++cc) {
        f32x4 acc[2][4];
        #pragma unroll
        for (int m = 0; m < 2; ++m)
            #pragma unroll
            for (int n = 0; n < 4; ++n)
                acc[m][n] = (f32x4){0.f, 0.f, 0.f, 0.f};

        #pragma unroll
        for (int kc = 0; kc < 4; ++kc) {
            short8 af[2], bq[4];
            #pragma unroll
            for (int m = 0; m < 2; ++m)
                af[m] = *reinterpret_cast<const short8*>(
                    &Ds[wr * 32 + m * 16 + (lane & 15)][kc * 32 + (lane >> 4) * 8]);
            #pragma unroll
            for (int n = 0; n < 4; ++n)
                bq[n] = *reinterpret_cast<const short8*>(
                    &Qs[wc * 64 + n * 16 + (lane & 15)][kc * 32 + (lane >> 4) * 8]);
            #pragma unroll
            for (int m = 0; m < 2; ++m)
                #pragma unroll
                for (int n = 0; n < 4; ++n)
                    acc[m][n] = __builtin_amdgcn_mfma_f32_16x16x32_bf16(af[m], bq[n], acc[m][n], 0, 0, 0);
        }
        __syncthreads();   // Ds reads done

        short8 st[4];
        if (cc < 7) {
            #pragma unroll
            for (int v = 0; v < 4; ++v)
                st[v] = *reinterpret_cast<const short8*>(
                    dbase + (size_t)((cc + 1) * 64 + dr) * NH + dc + v * 8);
        }

        // Gaussian soft-histogram via recurrence outward from k=4.
        #pragma unroll
        for (int n = 0; n < 4; ++n)
            #pragma unroll
            for (int m = 0; m < 2; ++m)
                #pragma unroll
                for (int i = 0; i < 4; ++i) {
                    float x = acc[m][n][i];
                    float R  = __builtin_amdgcn_exp2f(x * 28.853900817779268f);   // e^{20x}
                    float Ri = __builtin_amdgcn_exp2f(x * -28.853900817779268f);  // e^{-20x}
                    float d4 = x + 0.1f;
                    float E4 = __builtin_amdgcn_exp2f(d4 * d4 * -72.134752044448169f);
                    sums[n][4] += E4;
                    float u = E4 * R;        sums[n][5] += u;
                    u *= R; u *= C1;         sums[n][6] += u;
                    u *= R; u *= C2;         sums[n][7] += u;
                    u *= R; u *= C3;         sums[n][8] += u;
                    u *= R; u *= C4;         sums[n][9] += u;
                    float w = E4 * Ri; w *= C1; sums[n][3] += w;
                    w *= Ri; w *= C2;        sums[n][2] += w;
                    w *= Ri; w *= C3;        sums[n][1] += w;
                    w *= Ri; w *= C4;        sums[n][0] += w;
                    float d1 = x - 1.0f;
                    sums[n][10] += __builtin_amdgcn_exp2f(d1 * d1 * -721347.52044448f);
                }

        if (cc < 7) {
            #pragma unroll
            for (int v = 0; v < 4; ++v)
                *reinterpret_cast<short8*>(&Ds[dr][dc + v * 8]) = st[v];
            __syncthreads();
        }
    }

    // reduce over d-row groups, combine wr halves (red aliases Ds -- safe now)
    #pragma unroll
    for (int n = 0; n < 4; ++n)
        #pragma unroll
        for (int k = 0; k < 11; ++k) {
            float s = sums[n][k];
            s += __shfl_xor(s, 16);
            s += __shfl_xor(s, 32);
            sums[n][k] = s;
        }
    if ((lane >> 4) == 0) {
        #pragma unroll
        for (int n = 0; n < 4; ++n)
            #pragma unroll
            for (int k = 0; k < 11; ++k)
                red[wr][wc * 64 + n * 16 + (lane & 15)][k] = sums[n][k];
    }
    __syncthreads();
    if (tid < 128) {
        float lv[11];
        #pragma unroll
        for (int k = 0; k < 11; ++k)
            lv[k] = log1pf(red[0][tid][k] + red[1][tid][k]);
        #pragma unroll
        for (int k = 0; k < 11; ++k) {
            float s = lv[k];
            s += __shfl_xor(s, 1); s += __shfl_xor(s, 2); s += __shfl_xor(s, 4);
            s += __shfl_xor(s, 8); s += __shfl_xor(s, 16); s += __shfl_xor(s, 32);
            lv[k] = s;
        }
        if ((tid & 63) == 0) {
            #pragma unroll
            for (int k = 0; k < 11; ++k) wsum[tid >> 6][k] = lv[k];
        }
    }
    __syncthreads();
    if (tid < 11) phi[b * 99 + pair * 11 + tid] = wsum[0][tid] + wsum[1][tid];
}

// ---------------- Stage 3: final linear ----------------
__global__ void final_kernel(const float* __restrict__ phi, const float* __restrict__ ow,
                             const float* __restrict__ obias, float* __restrict__ out)
{
    int b = threadIdx.x;
    float s = obias[0];
    #pragma unroll
    for (int j = 0; j < 99; ++j) s += phi[b * 99 + j] * ow[j];
    out[b] = s;
}

extern "C" void kernel_launch(void* const* d_in, const int* in_sizes, int n_in,
                              void* d_out, int out_size, void* d_ws, size_t ws_size,
                              hipStream_t stream)
{
    const int*   query = (const int*)d_in[0];
    const int*   doc   = (const int*)d_in[1];
    const float* q_emb = (const float*)d_in[2];
    const float* d_emb = (const float*)d_in[3];
    const float* out_w = (const float*)d_in[4];
    const float* out_b = (const float*)d_in[5];
    const float* cw0 = (const float*)d_in[6];
    const float* cb0 = (const float*)d_in[7];
    const float* cw1 = (const float*)d_in[8];
    const float* cb1 = (const float*)d_in[9];
    const float* cw2 = (const float*)d_in[10];
    const float* cb2 = (const float*)d_in[11];

    const size_t QN = (size_t)NB * NLQ * NH;
    const size_t DN = (size_t)NB * NLD * NH;

    bf16* Wp = (bf16*)d_ws;
    bf16* qn = Wp + 368640;
    bf16* dn = qn + 3 * QN;
    float* phi = (float*)(dn + 3 * DN);

    pack_w<<<dim3(640, 3), 256, 0, stream>>>(cw0, cw1, cw2, Wp);
    conv_kernel<<<960, 512, 0, stream>>>(query, doc, q_emb, d_emb, Wp, cb0, cb1, cb2, qn, dn);
    sim_kernel<<<NB * 9, 256, 0, stream>>>(qn, dn, phi);
    final_kernel<<<1, 128, 0, stream>>>(phi, out_w, out_b, (float*)d_out);
}

// Round 8
// 278.576 us; speedup vs baseline: 4.7298x; 4.7298x over previous
//
#include <hip/hip_runtime.h>
#include <hip/hip_bf16.h>

typedef __hip_bfloat16 bf16;
typedef __attribute__((ext_vector_type(8))) short short8;
typedef __attribute__((ext_vector_type(4))) short short4v;
typedef __attribute__((ext_vector_type(4))) float f32x4;

#define NB 128
#define NH 128
#define NLQ 128
#define NLD 512
#define NEMB 300

__device__ __forceinline__ unsigned short bfbits(float x) {
    __hip_bfloat16 h = __float2bfloat16(x);
    return *reinterpret_cast<unsigned short*>(&h);
}

__device__ __forceinline__ float fast_tanh(float x) {
    x = fminf(9.f, fmaxf(-9.f, x));
    float e = __builtin_amdgcn_exp2f(x * 2.8853900817779268f); // e^{2x}
    return (e - 1.f) * __builtin_amdgcn_rcpf(e + 1.f);
}

// ---------------- Stage 0: pack conv weights, cc-major: [cc][t][h][c'] ------
__global__ void pack_w(const float* __restrict__ cw0, const float* __restrict__ cw1,
                       const float* __restrict__ cw2, bf16* __restrict__ Wp)
{
    int widx = blockIdx.y;
    int W = widx + 2;
    int e = blockIdx.x * 256 + threadIdx.x;
    if (e >= W * 40960) return;
    int ch = e >> 12;            // chunk = 4096 bf16
    int cc = ch / W;
    int t  = ch - cc * W;
    int h  = (e >> 5) & 127;
    int cp = e & 31;
    int c  = cc * 32 + cp;
    const float* cw = (widx == 0) ? cw0 : (widx == 1 ? cw1 : cw2);
    float v = (c < NEMB) ? cw[(h * NEMB + c) * W + t] : 0.f;
    size_t off = (widx == 0) ? 0 : (widx == 1 ? 81920 : 204800);
    Wp[off + e] = __float2bfloat16(v);
}

// ---------------- Stage 1: gather + conv + tanh + l2norm ----------------
// 256(l)x128(h) tile, 8 waves (4r x 2c) of 64x64. A (gathered X) through LDS,
// single-buffered, 2 barriers per 32-col chunk. B (weights) read DIRECTLY from
// global Wp each step (1KB-contiguous per-wave fragments, L1/L2-resident).
// launch_bounds(512,4): VGPR cap 128 -- (512,8) capped at 64 and spilled
// everything to scratch (round-7 regression: 3.4GB scratch writes).
__global__ __launch_bounds__(512, 4)
void conv_kernel(const int* __restrict__ q_tok, const int* __restrict__ d_tok,
                 const float* __restrict__ q_emb, const float* __restrict__ d_emb,
                 const bf16* __restrict__ Wp,
                 const float* __restrict__ cb0, const float* __restrict__ cb1,
                 const float* __restrict__ cb2,
                 bf16* __restrict__ qn, bf16* __restrict__ dn)
{
    __shared__ bf16 Xs[2][132][40];      // [subtile][row][col]; single K-chunk buffer
    __shared__ int tokLds[2][132];
    __shared__ float ssq[2][256];

    int bx = blockIdx.x;
    int widx = bx % 3;
    int inner = bx / 3;
    int W = widx + 2;
    const bf16* wp = Wp + ((widx == 0) ? 0 : (widx == 1 ? 81920 : 204800));
    const float* cb = (widx == 0) ? cb0 : (widx == 1 ? cb1 : cb2);

    const int* toks; const float* emb; bf16* outp; int L;
    int sb0, sb1, sl00, sl01;
    if (inner < 64) {
        toks = q_tok; emb = q_emb; outp = qn + (size_t)widx * NB * NLQ * NH;
        L = NLQ; sb0 = inner * 2; sb1 = sb0 + 1; sl00 = 0; sl01 = 0;
    } else {
        int i = inner - 64;
        toks = d_tok; emb = d_emb; outp = dn + (size_t)widx * NB * NLD * NH;
        L = NLD; sb0 = i >> 1; sb1 = sb0; sl00 = (i & 1) * 256; sl01 = sl00 + 128;
    }

    int tid = threadIdx.x;
    int lane = tid & 63;
    int wv = tid >> 6;
    int wr = wv >> 1;     // 0..3 (row quarter)
    int wc = wv & 1;      // 0..1 (col half)
    int s_wave = wr >> 1;
    int lr_base = (wr & 1) * 64;

    // ---- tokens ----
    if (tid < 132) {
        int l = sl00 + tid;
        tokLds[0][tid] = (l < L) ? toks[sb0 * L + l] : -1;
    } else if (tid >= 256 && tid < 388) {
        int rr = tid - 256;
        int l = sl01 + rr;
        tokLds[1][rr] = (l < L) ? toks[sb1 * L + l] : -1;
    }
    __syncthreads();

    // ---- X staging helpers (main: 2 thr/row rows 0..255; tail: thr 448+ rows 128..131) ----
    auto xload_main = [&](int cc, float4* v) {
        int u = tid >> 1, s = u >> 7, rr = u & 127, half = tid & 1;
        int tok = tokLds[s][rr];
        int cbase = cc * 32 + half * 16;
        #pragma unroll
        for (int qq = 0; qq < 4; ++qq) {
            int c = cbase + qq * 4;
            float4 x = make_float4(0.f, 0.f, 0.f, 0.f);
            if (tok >= 0 && c < NEMB)
                x = *reinterpret_cast<const float4*>(emb + (size_t)tok * NEMB + c);
            v[qq] = x;
        }
    };
    auto xwrite_main = [&](const float4* v) {
        int u = tid >> 1, s = u >> 7, rr = u & 127, half = tid & 1;
        short8 o0, o1;
        o0[0] = (short)bfbits(v[0].x); o0[1] = (short)bfbits(v[0].y);
        o0[2] = (short)bfbits(v[0].z); o0[3] = (short)bfbits(v[0].w);
        o0[4] = (short)bfbits(v[1].x); o0[5] = (short)bfbits(v[1].y);
        o0[6] = (short)bfbits(v[1].z); o0[7] = (short)bfbits(v[1].w);
        o1[0] = (short)bfbits(v[2].x); o1[1] = (short)bfbits(v[2].y);
        o1[2] = (short)bfbits(v[2].z); o1[3] = (short)bfbits(v[2].w);
        o1[4] = (short)bfbits(v[3].x); o1[5] = (short)bfbits(v[3].y);
        o1[6] = (short)bfbits(v[3].z); o1[7] = (short)bfbits(v[3].w);
        *reinterpret_cast<short8*>(&Xs[s][rr][half * 16]) = o0;
        *reinterpret_cast<short8*>(&Xs[s][rr][half * 16 + 8]) = o1;
    };
    auto xload_tail = [&](int cc, float4& x) {
        int j = tid - 448, trow = j >> 3, s = trow >> 2, rr = 128 + (trow & 3), qq = j & 7;
        int tok = tokLds[s][rr];
        int c = cc * 32 + qq * 4;
        x = make_float4(0.f, 0.f, 0.f, 0.f);
        if (tok >= 0 && c < NEMB)
            x = *reinterpret_cast<const float4*>(emb + (size_t)tok * NEMB + c);
    };
    auto xwrite_tail = [&](const float4& x) {
        int j = tid - 448, trow = j >> 3, s = trow >> 2, rr = 128 + (trow & 3), qq = j & 7;
        short4v o;
        o[0] = (short)bfbits(x.x); o[1] = (short)bfbits(x.y);
        o[2] = (short)bfbits(x.z); o[3] = (short)bfbits(x.w);
        *reinterpret_cast<short4v*>(&Xs[s][rr][qq * 4]) = o;
    };

    // ---- prologue: stage X chunk 0 ----
    {
        float4 v[4];
        xload_main(0, v);
        float4 xt;
        if (tid >= 448) xload_tail(0, xt);
        xwrite_main(v);
        if (tid >= 448) xwrite_tail(xt);
    }
    __syncthreads();

    f32x4 acc[4][4];
    #pragma unroll
    for (int m = 0; m < 4; ++m)
        #pragma unroll
        for (int n = 0; n < 4; ++n)
            acc[m][n] = (f32x4){0.f, 0.f, 0.f, 0.f};

    const short8* wp8 = reinterpret_cast<const short8*>(wp);
    float4 xv[4]; float4 xtl;

    for (int cc = 0; cc < 10; ++cc) {
        if (cc < 9) {      // issue next-chunk gather early; consumed after t-loop
            xload_main(cc + 1, xv);
            if (tid >= 448) xload_tail(cc + 1, xtl);
        }
        for (int t = 0; t < W; ++t) {
            int so = (cc * W + t) * 512;
            short8 bv[4];
            #pragma unroll
            for (int n = 0; n < 4; ++n)
                bv[n] = wp8[so + (wc * 64 + n * 16 + (lane & 15)) * 4 + (lane >> 4)];
            #pragma unroll
            for (int m = 0; m < 4; ++m) {
                short8 af = *reinterpret_cast<const short8*>(
                    &Xs[s_wave][lr_base + m * 16 + (lane & 15) + t][(lane >> 4) * 8]);
                #pragma unroll
                for (int n = 0; n < 4; ++n)
                    acc[m][n] = __builtin_amdgcn_mfma_f32_16x16x32_bf16(af, bv[n], acc[m][n], 0, 0, 0);
            }
        }
        if (cc < 9) {
            __syncthreads();          // all waves done reading this chunk
            xwrite_main(xv);
            if (tid >= 448) xwrite_tail(xtl);
            __syncthreads();          // new chunk visible
        }
    }

    // ---- epilogue: bias + tanh, row l2norm, store ----
    float ssl[4][4];
    #pragma unroll
    for (int m = 0; m < 4; ++m)
        #pragma unroll
        for (int i = 0; i < 4; ++i) ssl[m][i] = 0.f;

    #pragma unroll
    for (int n = 0; n < 4; ++n) {
        float bias = cb[wc * 64 + n * 16 + (lane & 15)];
        #pragma unroll
        for (int m = 0; m < 4; ++m)
            #pragma unroll
            for (int i = 0; i < 4; ++i) {
                float v = fast_tanh(acc[m][n][i] + bias);
                acc[m][n][i] = v;
                ssl[m][i] += v * v;
            }
    }
    #pragma unroll
    for (int m = 0; m < 4; ++m)
        #pragma unroll
        for (int i = 0; i < 4; ++i) {
            float s = ssl[m][i];
            s += __shfl_xor(s, 1); s += __shfl_xor(s, 2);
            s += __shfl_xor(s, 4); s += __shfl_xor(s, 8);
            ssl[m][i] = s;
        }
    if ((lane & 15) == 0) {
        #pragma unroll
        for (int m = 0; m < 4; ++m)
            #pragma unroll
            for (int i = 0; i < 4; ++i)
                ssq[wc][wr * 64 + m * 16 + (lane >> 4) * 4 + i] = ssl[m][i];
    }
    __syncthreads();
    #pragma unroll
    for (int m = 0; m < 4; ++m)
        #pragma unroll
        for (int i = 0; i < 4; ++i) {
            int r = wr * 64 + m * 16 + (lane >> 4) * 4 + i;
            float s2 = ssq[0][r] + ssq[1][r];
            float sc = 1.f / fmaxf(sqrtf(s2), 1e-12f);
            int s = r >> 7, lr = r & 127;
            int b = s ? sb1 : sb0;
            int l = (s ? sl01 : sl00) + lr;
            bf16* dst = outp + ((size_t)(b * L + l)) * NH;
            #pragma unroll
            for (int n = 0; n < 4; ++n)
                dst[wc * 64 + n * 16 + (lane & 15)] = __float2bfloat16(acc[m][n][i] * sc);
        }
}

// ---------------- Stage 2: S^T = D*Q^T, recurrence pooling ----------
// 8 chunks of 64 d-rows; red aliases Ds; LDS ~52.3KB -> 3 blocks/CU.
__global__ __launch_bounds__(256, 4)
void sim_kernel(const bf16* __restrict__ qn, const bf16* __restrict__ dn,
                float* __restrict__ phi)
{
    __shared__ bf16 Qs[128][136];
    __shared__ bf16 Ds[64][136];
    __shared__ float wsum[2][11];
    float (*red)[128][11] = reinterpret_cast<float(*)[128][11]>(&Ds[0][0]); // alias (disjoint in time)

    int blk = blockIdx.x;
    int b = blk / 9;
    int pair = blk - b * 9;
    int qi = pair / 3, di = pair - qi * 3;

    int tid = threadIdx.x, lane = tid & 63, wv = tid >> 6, wr = wv >> 1, wc = wv & 1;

    const bf16* qbase = qn + ((size_t)qi * NB + b) * (NLQ * NH);
    const bf16* dbase = dn + ((size_t)di * NB + b) * (NLD * NH);

    // stage Q (128x128): 2 thr/row
    {
        int r = tid >> 1, h0 = (tid & 1) * 64;
        #pragma unroll
        for (int v = 0; v < 8; ++v)
            *reinterpret_cast<short8*>(&Qs[r][h0 + v * 8]) =
                *reinterpret_cast<const short8*>(qbase + (size_t)r * NH + h0 + v * 8);
    }

    // stage D chunk 0 (64 rows): 4 thr/row
    int dr = tid >> 2, dc = (tid & 3) * 32;
    {
        short8 st[4];
        #pragma unroll
        for (int v = 0; v < 4; ++v)
            st[v] = *reinterpret_cast<const short8*>(dbase + (size_t)dr * NH + dc + v * 8);
        #pragma unroll
        for (int v = 0; v < 4; ++v)
            *reinterpret_cast<short8*>(&Ds[dr][dc + v * 8]) = st[v];
    }
    __syncthreads();

    float sums[4][11];
    #pragma unroll
    for (int n = 0; n < 4; ++n)
        #pragma unroll
        for (int k = 0; k < 11; ++k) sums[n][k] = 0.f;

    const float C1 = 1.8315638888734179e-2f;   // e^-4
    const float C2 = 3.3546262790251185e-4f;   // e^-8
    const float C3 = 6.1442123533282098e-6f;   // e^-12
    const float C4 = 1.1253517471925912e-7f;   // e^-16

    for (int cc = 0; cc < 8; ++cc) {
        f32x4 acc[2][4];
        #pragma unroll
        for (int m = 0; m < 2; ++m)
            #pragma unroll
            for (int n = 0; n < 4; ++n)
                acc[m][n] = (f32x4){0.f, 0.f, 0.f, 0.f};

        #pragma unroll
        for (int kc = 0; kc < 4; ++kc) {
            short8 af[2], bq[4];
            #pragma unroll
            for (int m = 0; m < 2; ++m)
                af[m] = *reinterpret_cast<const short8*>(
                    &Ds[wr * 32 + m * 16 + (lane & 15)][kc * 32 + (lane >> 4) * 8]);
            #pragma unroll
            for (int n = 0; n < 4; ++n)
                bq[n] = *reinterpret_cast<const short8*>(
                    &Qs[wc * 64 + n * 16 + (lane & 15)][kc * 32 + (lane >> 4) * 8]);
            #pragma unroll
            for (int m = 0; m < 2; ++m)
                #pragma unroll
                for (int n = 0; n < 4; ++n)
                    acc[m][n] = __builtin_amdgcn_mfma_f32_16x16x32_bf16(af[m], bq[n], acc[m][n], 0, 0, 0);
        }
        __syncthreads();   // Ds reads done

        short8 st[4];
        if (cc < 7) {
            #pragma unroll
            for (int v = 0; v < 4; ++v)
                st[v] = *reinterpret_cast<const short8*>(
                    dbase + (size_t)((cc + 1) * 64 + dr) * NH + dc + v * 8);
        }

        // Gaussian soft-histogram via recurrence outward from k=4.
        #pragma unroll
        for (int n = 0; n < 4; ++n)
            #pragma unroll
            for (int m = 0; m < 2; ++m)
                #pragma unroll
                for (int i = 0; i < 4; ++i) {
                    float x = acc[m][n][i];
                    float R  = __builtin_amdgcn_exp2f(x * 28.853900817779268f);   // e^{20x}
                    float Ri = __builtin_amdgcn_exp2f(x * -28.853900817779268f);  // e^{-20x}
                    float d4 = x + 0.1f;
                    float E4 = __builtin_amdgcn_exp2f(d4 * d4 * -72.134752044448169f);
                    sums[n][4] += E4;
                    float u = E4 * R;        sums[n][5] += u;
                    u *= R; u *= C1;         sums[n][6] += u;
                    u *= R; u *= C2;         sums[n][7] += u;
                    u *= R; u *= C3;         sums[n][8] += u;
                    u *= R; u *= C4;         sums[n][9] += u;
                    float w = E4 * Ri; w *= C1; sums[n][3] += w;
                    w *= Ri; w *= C2;        sums[n][2] += w;
                    w *= Ri; w *= C3;        sums[n][1] += w;
                    w *= Ri; w *= C4;        sums[n][0] += w;
                    float d1 = x - 1.0f;
                    sums[n][10] += __builtin_amdgcn_exp2f(d1 * d1 * -721347.52044448f);
                }

        if (cc < 7) {
            #pragma unroll
            for (int v = 0; v < 4; ++v)
                *reinterpret_cast<short8*>(&Ds[dr][dc + v * 8]) = st[v];
            __syncthreads();
        }
    }

    // reduce over d-row groups, combine wr halves (red aliases Ds -- safe now)
    #pragma unroll
    for (int n = 0; n < 4; ++n)
        #pragma unroll
        for (int k = 0; k < 11; ++k) {
            float s = sums[n][k];
            s += __shfl_xor(s, 16);
            s += __shfl_xor(s, 32);
            sums[n][k] = s;
        }
    if ((lane >> 4) == 0) {
        #pragma unroll
        for (int n = 0; n < 4; ++n)
            #pragma unroll
            for (int k = 0; k < 11; ++k)
                red[wr][wc * 64 + n * 16 + (lane & 15)][k] = sums[n][k];
    }
    __syncthreads();
    if (tid < 128) {
        float lv[11];
        #pragma unroll
        for (int k = 0; k < 11; ++k)
            lv[k] = log1pf(red[0][tid][k] + red[1][tid][k]);
        #pragma unroll
        for (int k = 0; k < 11; ++k) {
            float s = lv[k];
            s += __shfl_xor(s, 1); s += __shfl_xor(s, 2); s += __shfl_xor(s, 4);
            s += __shfl_xor(s, 8); s += __shfl_xor(s, 16); s += __shfl_xor(s, 32);
            lv[k] = s;
        }
        if ((tid & 63) == 0) {
            #pragma unroll
            for (int k = 0; k < 11; ++k) wsum[tid >> 6][k] = lv[k];
        }
    }
    __syncthreads();
    if (tid < 11) phi[b * 99 + pair * 11 + tid] = wsum[0][tid] + wsum[1][tid];
}

// ---------------- Stage 3: final linear ----------------
__global__ void final_kernel(const float* __restrict__ phi, const float* __restrict__ ow,
                             const float* __restrict__ obias, float* __restrict__ out)
{
    int b = threadIdx.x;
    float s = obias[0];
    #pragma unroll
    for (int j = 0; j < 99; ++j) s += phi[b * 99 + j] * ow[j];
    out[b] = s;
}

extern "C" void kernel_launch(void* const* d_in, const int* in_sizes, int n_in,
                              void* d_out, int out_size, void* d_ws, size_t ws_size,
                              hipStream_t stream)
{
    const int*   query = (const int*)d_in[0];
    const int*   doc   = (const int*)d_in[1];
    const float* q_emb = (const float*)d_in[2];
    const float* d_emb = (const float*)d_in[3];
    const float* out_w = (const float*)d_in[4];
    const float* out_b = (const float*)d_in[5];
    const float* cw0 = (const float*)d_in[6];
    const float* cb0 = (const float*)d_in[7];
    const float* cw1 = (const float*)d_in[8];
    const float* cb1 = (const float*)d_in[9];
    const float* cw2 = (const float*)d_in[10];
    const float* cb2 = (const float*)d_in[11];

    const size_t QN = (size_t)NB * NLQ * NH;
    const size_t DN = (size_t)NB * NLD * NH;

    bf16* Wp = (bf16*)d_ws;
    bf16* qn = Wp + 368640;
    bf16* dn = qn + 3 * QN;
    float* phi = (float*)(dn + 3 * DN);

    pack_w<<<dim3(640, 3), 256, 0, stream>>>(cw0, cw1, cw2, Wp);
    conv_kernel<<<960, 512, 0, stream>>>(query, doc, q_emb, d_emb, Wp, cb0, cb1, cb2, qn, dn);
    sim_kernel<<<NB * 9, 256, 0, stream>>>(qn, dn, phi);
    final_kernel<<<1, 128, 0, stream>>>(phi, out_w, out_b, (float*)d_out);
}